// Round 1
// baseline (514.461 us; speedup 1.0000x reference)
//
#include <hip/hip_runtime.h>

#define DEV static __device__ __forceinline__

using f32x4 = __attribute__((ext_vector_type(4))) float;
using s16x8 = __attribute__((ext_vector_type(8))) short;   // 8 bf16 in 4 VGPRs

DEV unsigned short f2bf(float x) {          // fp32 -> bf16 bits, RNE
    unsigned int u = __float_as_uint(x);
    unsigned int r = (u + 0x7FFFu + ((u >> 16) & 1u)) >> 16;
    return (unsigned short)r;
}
DEV float bf2f(unsigned short u) {          // bf16 bits -> fp32 (exact)
    return __uint_as_float(((unsigned int)u) << 16);
}

DEV f32x4 mfma16(s16x8 a, s16x8 b, f32x4 c) {
    return __builtin_amdgcn_mfma_f32_16x16x32_bf16(a, b, c, 0, 0, 0);
}

// ---------------------------------------------------------------------------
// split fp32 -> (hi, lo) bf16 planes
__global__ void k_split(const float* __restrict__ in, unsigned short* __restrict__ hi,
                        unsigned short* __restrict__ lo, int n4) {
    for (int i = blockIdx.x * blockDim.x + threadIdx.x; i < n4; i += gridDim.x * blockDim.x) {
        float4 v = ((const float4*)in)[i];
        ushort4 h, l;
        h.x = f2bf(v.x); l.x = f2bf(v.x - bf2f(h.x));
        h.y = f2bf(v.y); l.y = f2bf(v.y - bf2f(h.y));
        h.z = f2bf(v.z); l.z = f2bf(v.z - bf2f(h.z));
        h.w = f2bf(v.w); l.w = f2bf(v.w - bf2f(h.w));
        ((ushort4*)hi)[i] = h;
        ((ushort4*)lo)[i] = l;
    }
}

// ---------------------------------------------------------------------------
// W [512][512] (k-major) -> Wt hi/lo planes [n][k], with scale folded in.
__global__ void k_wsplit(const float* __restrict__ W, unsigned short* __restrict__ Thi,
                         unsigned short* __restrict__ Tlo, float scale) {
    __shared__ float tile[64][65];
    int bk = (blockIdx.x >> 3) * 64, bn = (blockIdx.x & 7) * 64;
    int t = threadIdx.x;
    int r = t >> 2, c4 = (t & 3) * 16;
#pragma unroll
    for (int j = 0; j < 16; j += 4) {
        float4 v = *(const float4*)&W[(size_t)(bk + r) * 512 + bn + c4 + j];
        tile[r][c4 + j + 0] = v.x; tile[r][c4 + j + 1] = v.y;
        tile[r][c4 + j + 2] = v.z; tile[r][c4 + j + 3] = v.w;
    }
    __syncthreads();
    int n = t >> 2, k4 = (t & 3) * 16;
#pragma unroll
    for (int j = 0; j < 16; ++j) {
        float x = tile[k4 + j][n] * scale;
        unsigned short h = f2bf(x);
        Thi[(size_t)(bn + n) * 512 + bk + k4 + j] = h;
        Tlo[(size_t)(bn + n) * 512 + bk + k4 + j] = f2bf(x - bf2f(h));
    }
}

// ---------------------------------------------------------------------------
// GEMM: C[8192x512] = A[8192x512] * B[512x512] + bias, via stacked-K' = 1536
// A segs [hi,hi,lo] x Bt segs [hi,lo,hi]  (Bt = B^T planes [n][k]).
// MODE 0: write bf16 hi/lo planes; MODE 1: write fp32.
template <int MODE>
__global__ __launch_bounds__(256, 2) void k_gemm(
    const unsigned short* __restrict__ Ahi, const unsigned short* __restrict__ Alo,
    const unsigned short* __restrict__ Bthi, const unsigned short* __restrict__ Btlo,
    const float* __restrict__ bias, float bscale,
    unsigned short* __restrict__ Chi, unsigned short* __restrict__ Clo,
    float* __restrict__ Cf) {
    __shared__ short As[128][40];
    __shared__ short Bs[128][40];
    int t = threadIdx.x, lane = t & 63, w = t >> 6;
    int wr = w >> 1, wc = w & 1, lr = lane & 15, lg = lane >> 4;
    int bm = (blockIdx.x >> 2) * 128, bn = (blockIdx.x & 3) * 128;
    f32x4 acc[4][4] = {};
    int srow = t >> 1, sko = (t & 1) * 16;
    for (int c = 0; c < 48; ++c) {
        int seg = c >> 4, kb = (c & 15) * 32;
        const unsigned short* Ap = (seg < 2) ? Ahi : Alo;
        const unsigned short* Bp = (seg == 1) ? Btlo : Bthi;
        const unsigned short* ag = Ap + (size_t)(bm + srow) * 512 + kb + sko;
        const unsigned short* bg = Bp + (size_t)(bn + srow) * 512 + kb + sko;
        s16x8 a0 = *(const s16x8*)(ag), a1 = *(const s16x8*)(ag + 8);
        s16x8 b0 = *(const s16x8*)(bg), b1 = *(const s16x8*)(bg + 8);
        *(s16x8*)&As[srow][sko] = a0; *(s16x8*)&As[srow][sko + 8] = a1;
        *(s16x8*)&Bs[srow][sko] = b0; *(s16x8*)&Bs[srow][sko + 8] = b1;
        __syncthreads();
        s16x8 af[4], bf[4];
#pragma unroll
        for (int i = 0; i < 4; ++i) af[i] = *(const s16x8*)&As[wr * 64 + i * 16 + lr][lg * 8];
#pragma unroll
        for (int i = 0; i < 4; ++i) bf[i] = *(const s16x8*)&Bs[wc * 64 + i * 16 + lr][lg * 8];
#pragma unroll
        for (int i = 0; i < 4; ++i)
#pragma unroll
            for (int j = 0; j < 4; ++j) acc[i][j] = mfma16(af[i], bf[j], acc[i][j]);
        __syncthreads();
    }
#pragma unroll
    for (int i = 0; i < 4; ++i)
#pragma unroll
        for (int j = 0; j < 4; ++j) {
            int m = bm + wr * 64 + i * 16 + lg * 4;
            int n = bn + wc * 64 + j * 16 + lr;
            float bv = bias[n] * bscale;
#pragma unroll
            for (int r = 0; r < 4; ++r) {
                float v = acc[i][j][r] + bv;
                if (MODE == 0) {
                    unsigned short hh = f2bf(v);
                    Chi[(size_t)(m + r) * 512 + n] = hh;
                    Clo[(size_t)(m + r) * 512 + n] = f2bf(v - bf2f(hh));
                } else {
                    Cf[(size_t)(m + r) * 512 + n] = v;
                }
            }
        }
}

// ---------------------------------------------------------------------------
// V planes [B*S][512] -> Vt planes [(b*8+h)*64 + d][4096]
__global__ void k_vt(const unsigned short* __restrict__ Vhi, const unsigned short* __restrict__ Vlo,
                     unsigned short* __restrict__ Vthi, unsigned short* __restrict__ Vtlo) {
    __shared__ unsigned short tile[64][72];
    int st = blockIdx.x & 63, bh = blockIdx.x >> 6;
    int b = bh >> 3, h = bh & 7;
    int t = threadIdx.x;
    int r = t >> 2, c = (t & 3) * 16;
    const unsigned short* src = Vhi;
    unsigned short* dst = Vthi;
#pragma unroll
    for (int pass = 0; pass < 2; ++pass) {
        size_t gin = (size_t)(b * 4096 + st * 64 + r) * 512 + h * 64 + c;
        *(s16x8*)&tile[r][c] = *(const s16x8*)&src[gin];
        *(s16x8*)&tile[r][c + 8] = *(const s16x8*)&src[gin + 8];
        __syncthreads();
        s16x8 o0, o1;
#pragma unroll
        for (int j = 0; j < 8; ++j) o0[j] = (short)tile[c + j][r];
#pragma unroll
        for (int j = 0; j < 8; ++j) o1[j] = (short)tile[c + 8 + j][r];
        size_t gout = (size_t)(bh * 64 + r) * 4096 + st * 64 + c;
        *(s16x8*)&dst[gout] = o0;
        *(s16x8*)&dst[gout + 8] = o1;
        __syncthreads();
        src = Vlo; dst = Vtlo;
    }
}

// ---------------------------------------------------------------------------
// Flash attention. Q,K planes [B*S][512] (col = h*64+d); Vt planes [bh*64+d][4096].
// Block: 4 waves, each wave 32 q-rows; KBLK = 64.
// Scores: mfma(a=K, b=Q) -> S[k][q], lane&15 = q. PV: mfma(a=Vt, b=P) -> O[d][q].
__global__ __launch_bounds__(256, 2) void k_attn(
    const unsigned short* __restrict__ Qhi, const unsigned short* __restrict__ Qlo,
    const unsigned short* __restrict__ Khi, const unsigned short* __restrict__ Klo,
    const unsigned short* __restrict__ Vthi, const unsigned short* __restrict__ Vtlo,
    unsigned short* __restrict__ Ohi, unsigned short* __restrict__ Olo) {
    __shared__ short Ks[64][136];        // cols [0:64] hi, [64:128] lo  (d')
    __shared__ short Vs[64][136];        // rows d, cols [0:64] k-hi, [64:128] k-lo
    __shared__ short Ps[4][4352];        // per-wave: P [32][136] (hi|lo), later O [32][68] f32
    int t = threadIdx.x, lane = t & 63, w = t >> 6;
    int lr = lane & 15, lg = lane >> 4;
    int qt = blockIdx.x & 31, bh = blockIdx.x >> 5;
    int b = bh >> 3, h = bh & 7;
    int qbase = qt * 128 + w * 32;

    s16x8 qr[2][4];                      // [qf][hi0,hi1,lo0,lo1]
#pragma unroll
    for (int qf = 0; qf < 2; ++qf) {
        size_t mrow = (size_t)(b * 4096 + qbase + qf * 16 + lr) * 512 + h * 64;
        qr[qf][0] = *(const s16x8*)&Qhi[mrow + lg * 8];
        qr[qf][1] = *(const s16x8*)&Qhi[mrow + 32 + lg * 8];
        qr[qf][2] = *(const s16x8*)&Qlo[mrow + lg * 8];
        qr[qf][3] = *(const s16x8*)&Qlo[mrow + 32 + lg * 8];
    }

    f32x4 oacc[4][2] = {};
    float mrun[2] = {-1e30f, -1e30f}, lrun[2] = {0.f, 0.f};
    const int ksoff[6] = {0, 32, 64, 96, 0, 32};   // K seg: hi,hi,lo,lo,hi,hi
    const int qci[6]   = {0, 1, 0, 1, 2, 3};       // Q seg: hi,hi,hi,hi,lo,lo
    const int poff[6]  = {0, 32, 64, 96, 0, 32};   // P seg: hi,hi,lo,lo,hi,hi
    const int voff[6]  = {0, 32, 0, 32, 64, 96};   // V seg: hi,hi,hi,hi,lo,lo
    short* pw = &Ps[w][0];

    for (int kt = 0; kt < 64; ++kt) {
        {   // stage K tile + Vt tile (all 256 threads)
            int row = t >> 2, p = t & 3;
            int db = (p & 1) * 32;
            const unsigned short* kg = ((p < 2) ? Khi : Klo) +
                (size_t)(b * 4096 + kt * 64 + row) * 512 + h * 64 + db;
            const unsigned short* vg = ((p < 2) ? Vthi : Vtlo) +
                (size_t)(bh * 64 + row) * 4096 + kt * 64 + db;
            s16x8 k0 = *(const s16x8*)(kg), k1 = *(const s16x8*)(kg + 8),
                  k2 = *(const s16x8*)(kg + 16), k3 = *(const s16x8*)(kg + 24);
            s16x8 v0 = *(const s16x8*)(vg), v1 = *(const s16x8*)(vg + 8),
                  v2 = *(const s16x8*)(vg + 16), v3 = *(const s16x8*)(vg + 24);
            *(s16x8*)&Ks[row][p * 32 + 0] = k0;  *(s16x8*)&Ks[row][p * 32 + 8] = k1;
            *(s16x8*)&Ks[row][p * 32 + 16] = k2; *(s16x8*)&Ks[row][p * 32 + 24] = k3;
            *(s16x8*)&Vs[row][p * 32 + 0] = v0;  *(s16x8*)&Vs[row][p * 32 + 8] = v1;
            *(s16x8*)&Vs[row][p * 32 + 16] = v2; *(s16x8*)&Vs[row][p * 32 + 24] = v3;
        }
        __syncthreads();

        // scores: S[k][q]
        f32x4 sacc[4][2] = {};
#pragma unroll
        for (int s = 0; s < 6; ++s)
#pragma unroll
            for (int kf = 0; kf < 4; ++kf) {
                s16x8 af = *(const s16x8*)&Ks[kf * 16 + lr][ksoff[s] + lg * 8];
                sacc[kf][0] = mfma16(af, qr[0][qci[s]], sacc[kf][0]);
                sacc[kf][1] = mfma16(af, qr[1][qci[s]], sacc[kf][1]);
            }

        // online softmax per qf (lane's q = qf*16 + lr; lane's k = kf*16 + lg*4 + r)
#pragma unroll
        for (int qf = 0; qf < 2; ++qf) {
            float tmax = -1e30f;
#pragma unroll
            for (int kf = 0; kf < 4; ++kf)
#pragma unroll
                for (int r = 0; r < 4; ++r) tmax = fmaxf(tmax, sacc[kf][qf][r]);
            tmax = fmaxf(tmax, __shfl_xor(tmax, 16));
            tmax = fmaxf(tmax, __shfl_xor(tmax, 32));
            float mnew = fmaxf(mrun[qf], tmax);
            float alpha = __expf(mrun[qf] - mnew);
            mrun[qf] = mnew;
            float tsum = 0.f;
#pragma unroll
            for (int kf = 0; kf < 4; ++kf)
#pragma unroll
                for (int r = 0; r < 4; ++r) {
                    float p = __expf(sacc[kf][qf][r] - mnew);
                    sacc[kf][qf][r] = p;
                    tsum += p;
                }
            tsum += __shfl_xor(tsum, 16);
            tsum += __shfl_xor(tsum, 32);
            lrun[qf] = lrun[qf] * alpha + tsum;
#pragma unroll
            for (int df = 0; df < 4; ++df) oacc[df][qf] *= alpha;

            int q = qf * 16 + lr;
#pragma unroll
            for (int kf = 0; kf < 4; ++kf) {
                int kcol = kf * 16 + lg * 4;
                float p0 = sacc[kf][qf][0], p1 = sacc[kf][qf][1];
                float p2 = sacc[kf][qf][2], p3 = sacc[kf][qf][3];
                unsigned short h0 = f2bf(p0), h1 = f2bf(p1), h2 = f2bf(p2), h3 = f2bf(p3);
                unsigned short l0 = f2bf(p0 - bf2f(h0)), l1 = f2bf(p1 - bf2f(h1));
                unsigned short l2 = f2bf(p2 - bf2f(h2)), l3 = f2bf(p3 - bf2f(h3));
                *(unsigned int*)&pw[q * 136 + kcol]          = (unsigned)h0 | ((unsigned)h1 << 16);
                *(unsigned int*)&pw[q * 136 + kcol + 2]      = (unsigned)h2 | ((unsigned)h3 << 16);
                *(unsigned int*)&pw[q * 136 + 64 + kcol]     = (unsigned)l0 | ((unsigned)l1 << 16);
                *(unsigned int*)&pw[q * 136 + 64 + kcol + 2] = (unsigned)l2 | ((unsigned)l3 << 16);
            }
        }

        // PV: O[d][q] += Vt' * P'
#pragma unroll
        for (int s = 0; s < 6; ++s) {
            s16x8 pf0 = *(const s16x8*)&pw[(0 + lr) * 136 + poff[s] + lg * 8];
            s16x8 pf1 = *(const s16x8*)&pw[(16 + lr) * 136 + poff[s] + lg * 8];
#pragma unroll
            for (int df = 0; df < 4; ++df) {
                s16x8 vf = *(const s16x8*)&Vs[df * 16 + lr][voff[s] + lg * 8];
                oacc[df][0] = mfma16(vf, pf0, oacc[df][0]);
                oacc[df][1] = mfma16(vf, pf1, oacc[df][1]);
            }
        }
        __syncthreads();
    }

    // epilogue: normalize, transpose O via per-wave LDS, write hi/lo planes
    float inv0 = 1.f / lrun[0], inv1 = 1.f / lrun[1];
    float* ow = (float*)&Ps[w][0];       // [32][68]
#pragma unroll
    for (int df = 0; df < 4; ++df) {
        f32x4 v0 = oacc[df][0] * inv0;
        f32x4 v1 = oacc[df][1] * inv1;
        *(f32x4*)&ow[(0 + lr) * 68 + df * 16 + lg * 4] = v0;
        *(f32x4*)&ow[(16 + lr) * 68 + df * 16 + lg * 4] = v1;
    }
#pragma unroll
    for (int p = 0; p < 2; ++p) {
        int q = p * 16 + (lane >> 2);
        int dc = (lane & 3) * 16;
        size_t gbase = (size_t)(b * 4096 + qbase + q) * 512 + h * 64 + dc;
        s16x8 hv0, hv1, lv0, lv1;
#pragma unroll
        for (int j = 0; j < 8; ++j) {
            float x = ow[q * 68 + dc + j];
            unsigned short hh = f2bf(x);
            hv0[j] = (short)hh; lv0[j] = (short)f2bf(x - bf2f(hh));
        }
#pragma unroll
        for (int j = 0; j < 8; ++j) {
            float x = ow[q * 68 + dc + 8 + j];
            unsigned short hh = f2bf(x);
            hv1[j] = (short)hh; lv1[j] = (short)f2bf(x - bf2f(hh));
        }
        *(s16x8*)&Ohi[gbase] = hv0;     *(s16x8*)&Ohi[gbase + 8] = hv1;
        *(s16x8*)&Olo[gbase] = lv0;     *(s16x8*)&Olo[gbase + 8] = lv1;
    }
}

// ---------------------------------------------------------------------------
extern "C" void kernel_launch(void* const* d_in, const int* in_sizes, int n_in,
                              void* d_out, int out_size, void* d_ws, size_t ws_size,
                              hipStream_t stream) {
    const float* x  = (const float*)d_in[0];
    const float* Wq = (const float*)d_in[1];
    const float* bq = (const float*)d_in[2];
    const float* Wk = (const float*)d_in[3];
    const float* bk = (const float*)d_in[4];
    const float* Wv = (const float*)d_in[5];
    const float* bv = (const float*)d_in[6];
    const float* Wo = (const float*)d_in[7];
    const float* bo = (const float*)d_in[8];
    float* out = (float*)d_out;

    char* ws = (char*)d_ws;
    const size_t PLANE = (size_t)8192 * 512 * 2;   // 8 MB (bf16 plane)
    const size_t WPL   = (size_t)512 * 512 * 2;    // 512 KB
    size_t off = 0;
    unsigned short* Xhi   = (unsigned short*)(ws + off); off += PLANE;
    unsigned short* Xlo   = (unsigned short*)(ws + off); off += PLANE;
    unsigned short* Wqthi = (unsigned short*)(ws + off); off += WPL;
    unsigned short* Wqtlo = (unsigned short*)(ws + off); off += WPL;
    unsigned short* Wkthi = (unsigned short*)(ws + off); off += WPL;
    unsigned short* Wktlo = (unsigned short*)(ws + off); off += WPL;
    unsigned short* Wvthi = (unsigned short*)(ws + off); off += WPL;
    unsigned short* Wvtlo = (unsigned short*)(ws + off); off += WPL;
    unsigned short* Wothi = (unsigned short*)(ws + off); off += WPL;
    unsigned short* Wotlo = (unsigned short*)(ws + off); off += WPL;
    unsigned short* Qhi   = (unsigned short*)(ws + off); off += PLANE;
    unsigned short* Qlo   = (unsigned short*)(ws + off); off += PLANE;
    unsigned short* Khi   = (unsigned short*)(ws + off); off += PLANE;
    unsigned short* Klo   = (unsigned short*)(ws + off); off += PLANE;
    unsigned short* Vhi   = (unsigned short*)(ws + off); off += PLANE;
    unsigned short* Vlo   = (unsigned short*)(ws + off); off += PLANE;
    unsigned short* Vthi  = (unsigned short*)(ws + off); off += PLANE;
    unsigned short* Vtlo  = (unsigned short*)(ws + off); off += PLANE;
    unsigned short* Ohi = Xhi;   // X is dead after the QKV GEMMs
    unsigned short* Olo = Xlo;

    k_split<<<1024, 256, 0, stream>>>(x, Xhi, Xlo, 8192 * 512 / 4);
    k_wsplit<<<64, 256, 0, stream>>>(Wq, Wqthi, Wqtlo, 0.125f);   // fold 1/sqrt(64) into Wq
    k_wsplit<<<64, 256, 0, stream>>>(Wk, Wkthi, Wktlo, 1.0f);
    k_wsplit<<<64, 256, 0, stream>>>(Wv, Wvthi, Wvtlo, 1.0f);
    k_wsplit<<<64, 256, 0, stream>>>(Wo, Wothi, Wotlo, 1.0f);
    k_gemm<0><<<256, 256, 0, stream>>>(Xhi, Xlo, Wqthi, Wqtlo, bq, 0.125f, Qhi, Qlo, nullptr);
    k_gemm<0><<<256, 256, 0, stream>>>(Xhi, Xlo, Wkthi, Wktlo, bk, 1.0f, Khi, Klo, nullptr);
    k_gemm<0><<<256, 256, 0, stream>>>(Xhi, Xlo, Wvthi, Wvtlo, bv, 1.0f, Vhi, Vlo, nullptr);
    k_vt<<<1024, 256, 0, stream>>>(Vhi, Vlo, Vthi, Vtlo);
    k_attn<<<512, 256, 0, stream>>>(Qhi, Qlo, Khi, Klo, Vthi, Vtlo, Ohi, Olo);
    k_gemm<1><<<256, 256, 0, stream>>>(Ohi, Olo, Wothi, Wotlo, bo, 1.0f, nullptr, nullptr, out);
}

// Round 4
// 482.514 us; speedup vs baseline: 1.0662x; 1.0662x over previous
//
#include <hip/hip_runtime.h>

#define DEV static __device__ __forceinline__

using f32x4 = __attribute__((ext_vector_type(4))) float;
using s16x8 = __attribute__((ext_vector_type(8))) short;   // 8 bf16 in 4 VGPRs

DEV unsigned short f2bf(float x) {          // fp32 -> bf16 bits, RNE
    unsigned int u = __float_as_uint(x);
    unsigned int r = (u + 0x7FFFu + ((u >> 16) & 1u)) >> 16;
    return (unsigned short)r;
}
DEV float bf2f(unsigned short u) {          // bf16 bits -> fp32 (exact)
    return __uint_as_float(((unsigned int)u) << 16);
}

DEV f32x4 mfma16(s16x8 a, s16x8 b, f32x4 c) {
    return __builtin_amdgcn_mfma_f32_16x16x32_bf16(a, b, c, 0, 0, 0);
}

DEV unsigned cvtpk_bf16(float a, float b) { // lo16 = bf16(a), hi16 = bf16(b)
    unsigned r;
    asm volatile("v_cvt_pk_bf16_f32 %0, %1, %2" : "=v"(r) : "v"(a), "v"(b));
    return r;
}
DEV float lo2f(unsigned h) { return __uint_as_float(h << 16); }
DEV float hi2f(unsigned h) { return __uint_as_float(h & 0xffff0000u); }

DEV void gload16(const unsigned short* g, short* l) {   // 16B global -> LDS direct
    __builtin_amdgcn_global_load_lds(
        (const __attribute__((address_space(1))) unsigned int*)g,
        (__attribute__((address_space(3))) unsigned int*)l, 16, 0, 0);
}

// ---------------------------------------------------------------------------
// split fp32 -> (hi, lo) bf16 planes
__global__ void k_split(const float* __restrict__ in, unsigned short* __restrict__ hi,
                        unsigned short* __restrict__ lo, int n4) {
    for (int i = blockIdx.x * blockDim.x + threadIdx.x; i < n4; i += gridDim.x * blockDim.x) {
        float4 v = ((const float4*)in)[i];
        ushort4 h, l;
        h.x = f2bf(v.x); l.x = f2bf(v.x - bf2f(h.x));
        h.y = f2bf(v.y); l.y = f2bf(v.y - bf2f(h.y));
        h.z = f2bf(v.z); l.z = f2bf(v.z - bf2f(h.z));
        h.w = f2bf(v.w); l.w = f2bf(v.w - bf2f(h.w));
        ((ushort4*)hi)[i] = h;
        ((ushort4*)lo)[i] = l;
    }
}

// ---------------------------------------------------------------------------
// W [512][512] (k-major) -> Wt hi/lo planes [n][k], with scale folded in.
__global__ void k_wsplit(const float* __restrict__ W, unsigned short* __restrict__ Thi,
                         unsigned short* __restrict__ Tlo, float scale) {
    __shared__ float tile[64][65];
    int bk = (blockIdx.x >> 3) * 64, bn = (blockIdx.x & 7) * 64;
    int t = threadIdx.x;
    int r = t >> 2, c4 = (t & 3) * 16;
#pragma unroll
    for (int j = 0; j < 16; j += 4) {
        float4 v = *(const float4*)&W[(size_t)(bk + r) * 512 + bn + c4 + j];
        tile[r][c4 + j + 0] = v.x; tile[r][c4 + j + 1] = v.y;
        tile[r][c4 + j + 2] = v.z; tile[r][c4 + j + 3] = v.w;
    }
    __syncthreads();
    int n = t >> 2, k4 = (t & 3) * 16;
#pragma unroll
    for (int j = 0; j < 16; ++j) {
        float x = tile[k4 + j][n] * scale;
        unsigned short h = f2bf(x);
        Thi[(size_t)(bn + n) * 512 + bk + k4 + j] = h;
        Tlo[(size_t)(bn + n) * 512 + bk + k4 + j] = f2bf(x - bf2f(h));
    }
}

// ---------------------------------------------------------------------------
// GEMM (m97 structure): C[8192x512] = A[8192x512]*B[512x512] + bias,
// stacked-K' = 1536: A segs [hi,hi,lo] x Bt segs [hi,lo,hi].
// global_load_lds width-16 staging into linear LDS [128][32] per K-step.
// NOTE: each 256-thread stage pass covers 2048 shorts (64 rows); second half
// lands at element offset 2048 (R2 bug was +4096 = LDS overflow into Bs).
template <int MODE>
__global__ __launch_bounds__(256, 2) void k_gemm(
    const unsigned short* __restrict__ Ahi, const unsigned short* __restrict__ Alo,
    const unsigned short* __restrict__ Bthi, const unsigned short* __restrict__ Btlo,
    const float* __restrict__ bias, float bscale,
    unsigned short* __restrict__ Chi, unsigned short* __restrict__ Clo,
    float* __restrict__ Cf) {
    __shared__ short As[128 * 32];
    __shared__ short Bs[128 * 32];
    int t = threadIdx.x, lane = t & 63, w = t >> 6;
    int wr = w >> 1, wc = w & 1, lr = lane & 15, lg = lane >> 4;
    int bm = (blockIdx.x >> 2) * 128, bn = (blockIdx.x & 3) * 128;
    f32x4 acc[4][4] = {};
    int srow = t >> 2, scol = (t & 3) * 8;          // 16B chunk per thread, rows 0-63 + 64-127
    for (int c = 0; c < 48; ++c) {
        int seg = c >> 4, kb = (c & 15) * 32;
        const unsigned short* Ap = (seg < 2) ? Ahi : Alo;
        const unsigned short* Bp = (seg == 1) ? Btlo : Bthi;
        const unsigned short* ag = Ap + (size_t)(bm + srow) * 512 + kb + scol;
        const unsigned short* bg = Bp + (size_t)(bn + srow) * 512 + kb + scol;
        gload16(ag, &As[t * 8]);
        gload16(ag + 64 * 512, &As[t * 8 + 2048]);
        gload16(bg, &Bs[t * 8]);
        gload16(bg + 64 * 512, &Bs[t * 8 + 2048]);
        __syncthreads();
        s16x8 af[4], bf[4];
#pragma unroll
        for (int i = 0; i < 4; ++i) af[i] = *(const s16x8*)&As[(wr * 64 + i * 16 + lr) * 32 + lg * 8];
#pragma unroll
        for (int i = 0; i < 4; ++i) bf[i] = *(const s16x8*)&Bs[(wc * 64 + i * 16 + lr) * 32 + lg * 8];
#pragma unroll
        for (int i = 0; i < 4; ++i)
#pragma unroll
            for (int j = 0; j < 4; ++j) acc[i][j] = mfma16(af[i], bf[j], acc[i][j]);
        __syncthreads();
    }
#pragma unroll
    for (int i = 0; i < 4; ++i)
#pragma unroll
        for (int j = 0; j < 4; ++j) {
            int m = bm + wr * 64 + i * 16 + lg * 4;
            int n = bn + wc * 64 + j * 16 + lr;
            float bv = bias[n] * bscale;
#pragma unroll
            for (int r = 0; r < 4; ++r) {
                float v = acc[i][j][r] + bv;
                if (MODE == 0) {
                    unsigned short hh = f2bf(v);
                    Chi[(size_t)(m + r) * 512 + n] = hh;
                    Clo[(size_t)(m + r) * 512 + n] = f2bf(v - bf2f(hh));
                } else {
                    Cf[(size_t)(m + r) * 512 + n] = v;
                }
            }
        }
}

// ---------------------------------------------------------------------------
// V planes [B*S][512] -> Vt planes [(b*8+h)*64 + d][4096]
__global__ void k_vt(const unsigned short* __restrict__ Vhi, const unsigned short* __restrict__ Vlo,
                     unsigned short* __restrict__ Vthi, unsigned short* __restrict__ Vtlo) {
    __shared__ unsigned short tile[64][72];
    int st = blockIdx.x & 63, bh = blockIdx.x >> 6;
    int b = bh >> 3, h = bh & 7;
    int t = threadIdx.x;
    int r = t >> 2, c = (t & 3) * 16;
    const unsigned short* src = Vhi;
    unsigned short* dst = Vthi;
#pragma unroll
    for (int pass = 0; pass < 2; ++pass) {
        size_t gin = (size_t)(b * 4096 + st * 64 + r) * 512 + h * 64 + c;
        *(s16x8*)&tile[r][c] = *(const s16x8*)&src[gin];
        *(s16x8*)&tile[r][c + 8] = *(const s16x8*)&src[gin + 8];
        __syncthreads();
        s16x8 o0, o1;
#pragma unroll
        for (int j = 0; j < 8; ++j) o0[j] = (short)tile[c + j][r];
#pragma unroll
        for (int j = 0; j < 8; ++j) o1[j] = (short)tile[c + 8 + j][r];
        size_t gout = (size_t)(bh * 64 + r) * 4096 + st * 64 + c;
        *(s16x8*)&dst[gout] = o0;
        *(s16x8*)&dst[gout + 8] = o1;
        __syncthreads();
        src = Vlo; dst = Vtlo;
    }
}

// ---------------------------------------------------------------------------
// Flash attention. Q,K planes [B*S][512] (col = h*64+d); Vt planes [bh*64+d][4096].
// Block: 4 waves, each wave 32 q-rows; KBLK = 64. Reg-prefetched staging.
// Scores: mfma(a=K, b=Q) -> S[k][q], lane&15 = q. PV: mfma(a=Vt, b=P) -> O[d][q].
__global__ __launch_bounds__(256, 2) void k_attn(
    const unsigned short* __restrict__ Qhi, const unsigned short* __restrict__ Qlo,
    const unsigned short* __restrict__ Khi, const unsigned short* __restrict__ Klo,
    const unsigned short* __restrict__ Vthi, const unsigned short* __restrict__ Vtlo,
    unsigned short* __restrict__ Ohi, unsigned short* __restrict__ Olo) {
    __shared__ short Ks[64][136];        // cols [0:64] hi, [64:128] lo  (d')
    __shared__ short Vs[64][136];        // rows d, cols [0:64] k-hi, [64:128] k-lo
    __shared__ short Ps[4][4352];        // per-wave: P [32][136] (hi|lo), later O [32][68] f32
    int t = threadIdx.x, lane = t & 63, w = t >> 6;
    int lr = lane & 15, lg = lane >> 4;
    int qt = blockIdx.x & 31, bh = blockIdx.x >> 5;
    int b = bh >> 3, h = bh & 7;
    int qbase = qt * 128 + w * 32;

    s16x8 qr[2][4];                      // [qf][hi0,hi1,lo0,lo1]
#pragma unroll
    for (int qf = 0; qf < 2; ++qf) {
        size_t mrow = (size_t)(b * 4096 + qbase + qf * 16 + lr) * 512 + h * 64;
        qr[qf][0] = *(const s16x8*)&Qhi[mrow + lg * 8];
        qr[qf][1] = *(const s16x8*)&Qhi[mrow + 32 + lg * 8];
        qr[qf][2] = *(const s16x8*)&Qlo[mrow + lg * 8];
        qr[qf][3] = *(const s16x8*)&Qlo[mrow + 32 + lg * 8];
    }

    f32x4 oacc[4][2] = {};
    float mrun[2] = {-1e30f, -1e30f}, lrun[2] = {0.f, 0.f};
    short* pw = &Ps[w][0];

    // staging bases: thread t covers (row = t>>2, plane/half-col p = t&3)
    int srow = t >> 2, p = t & 3;
    int db = (p & 1) * 32;
    const unsigned short* Kbase = ((p < 2) ? Khi : Klo) +
        (size_t)(b * 4096 + srow) * 512 + h * 64 + db;
    const unsigned short* Vbase = ((p < 2) ? Vthi : Vtlo) +
        (size_t)(bh * 64 + srow) * 4096 + db;

    s16x8 kst[4], vst[4];
    {   // prologue: load tile 0 into regs
        const unsigned short* kg = Kbase;             // kt=0
        const unsigned short* vg = Vbase;
        kst[0] = *(const s16x8*)(kg);      kst[1] = *(const s16x8*)(kg + 8);
        kst[2] = *(const s16x8*)(kg + 16); kst[3] = *(const s16x8*)(kg + 24);
        vst[0] = *(const s16x8*)(vg);      vst[1] = *(const s16x8*)(vg + 8);
        vst[2] = *(const s16x8*)(vg + 16); vst[3] = *(const s16x8*)(vg + 24);
    }

    for (int kt = 0; kt < 64; ++kt) {
        // write staged regs -> LDS
        *(s16x8*)&Ks[srow][p * 32 + 0] = kst[0];  *(s16x8*)&Ks[srow][p * 32 + 8] = kst[1];
        *(s16x8*)&Ks[srow][p * 32 + 16] = kst[2]; *(s16x8*)&Ks[srow][p * 32 + 24] = kst[3];
        *(s16x8*)&Vs[srow][p * 32 + 0] = vst[0];  *(s16x8*)&Vs[srow][p * 32 + 8] = vst[1];
        *(s16x8*)&Vs[srow][p * 32 + 16] = vst[2]; *(s16x8*)&Vs[srow][p * 32 + 24] = vst[3];
        // prefetch next tile into regs (survives the barrier; lands under compute)
        {
            int ktn = (kt < 63) ? kt + 1 : 63;
            const unsigned short* kg = Kbase + (size_t)ktn * 64 * 512;
            const unsigned short* vg = Vbase + ktn * 64;
            kst[0] = *(const s16x8*)(kg);      kst[1] = *(const s16x8*)(kg + 8);
            kst[2] = *(const s16x8*)(kg + 16); kst[3] = *(const s16x8*)(kg + 24);
            vst[0] = *(const s16x8*)(vg);      vst[1] = *(const s16x8*)(vg + 8);
            vst[2] = *(const s16x8*)(vg + 16); vst[3] = *(const s16x8*)(vg + 24);
        }
        __syncthreads();

        // ---- scores: S[k][q] = Khi.Qhi + Klo.Qhi + Khi.Qlo (d-chunked) ----
        f32x4 sacc[4][2] = {};
        __builtin_amdgcn_s_setprio(1);
#pragma unroll
        for (int kk = 0; kk < 4; ++kk) {            // koff = kk*32: hi d0,d1, lo d0,d1
            int qa = kk & 1;
#pragma unroll
            for (int kf = 0; kf < 4; ++kf) {
                s16x8 af = *(const s16x8*)&Ks[kf * 16 + lr][kk * 32 + lg * 8];
                sacc[kf][0] = mfma16(af, qr[0][qa], sacc[kf][0]);
                sacc[kf][1] = mfma16(af, qr[1][qa], sacc[kf][1]);
                if (kk < 2) {                        // K-hi also pairs with Q-lo
                    sacc[kf][0] = mfma16(af, qr[0][qa + 2], sacc[kf][0]);
                    sacc[kf][1] = mfma16(af, qr[1][qa + 2], sacc[kf][1]);
                }
            }
        }
        __builtin_amdgcn_s_setprio(0);

        // ---- online softmax + P pack (cvt_pk) ----
#pragma unroll
        for (int qf = 0; qf < 2; ++qf) {
            float tmax = -1e30f;
#pragma unroll
            for (int kf = 0; kf < 4; ++kf)
#pragma unroll
                for (int r = 0; r < 4; ++r) tmax = fmaxf(tmax, sacc[kf][qf][r]);
            tmax = fmaxf(tmax, __shfl_xor(tmax, 16));
            tmax = fmaxf(tmax, __shfl_xor(tmax, 32));
            float mnew = fmaxf(mrun[qf], tmax);
            float alpha = __expf(mrun[qf] - mnew);
            mrun[qf] = mnew;
            float tsum = 0.f;
#pragma unroll
            for (int kf = 0; kf < 4; ++kf)
#pragma unroll
                for (int r = 0; r < 4; ++r) {
                    float pv = __expf(sacc[kf][qf][r] - mnew);
                    sacc[kf][qf][r] = pv;
                    tsum += pv;
                }
            tsum += __shfl_xor(tsum, 16);
            tsum += __shfl_xor(tsum, 32);
            lrun[qf] = lrun[qf] * alpha + tsum;
#pragma unroll
            for (int df = 0; df < 4; ++df) oacc[df][qf] *= alpha;

            int q = qf * 16 + lr;
#pragma unroll
            for (int kf = 0; kf < 4; ++kf) {
                int kcol = kf * 16 + lg * 4;
                float p0 = sacc[kf][qf][0], p1 = sacc[kf][qf][1];
                float p2 = sacc[kf][qf][2], p3 = sacc[kf][qf][3];
                unsigned h01 = cvtpk_bf16(p0, p1), h23 = cvtpk_bf16(p2, p3);
                float r0 = p0 - lo2f(h01), r1 = p1 - hi2f(h01);
                float r2 = p2 - lo2f(h23), r3 = p3 - hi2f(h23);
                unsigned l01 = cvtpk_bf16(r0, r1), l23 = cvtpk_bf16(r2, r3);
                uint2 hv; hv.x = h01; hv.y = h23;
                uint2 lv; lv.x = l01; lv.y = l23;
                *(uint2*)&pw[q * 136 + kcol]      = hv;
                *(uint2*)&pw[q * 136 + 64 + kcol] = lv;
            }
        }

        // ---- PV: O[d][q] += Vhi.Phi + Vhi.Plo + Vlo.Phi (k-chunked) ----
        s16x8 pfr[2][4];                  // resident P frags: [qf][poff 0,32,64,96]
#pragma unroll
        for (int qf = 0; qf < 2; ++qf)
#pragma unroll
            for (int pp = 0; pp < 4; ++pp)
                pfr[qf][pp] = *(const s16x8*)&pw[(qf * 16 + lr) * 136 + pp * 32 + lg * 8];
        __builtin_amdgcn_s_setprio(1);
#pragma unroll
        for (int vv = 0; vv < 4; ++vv) {            // voff = vv*32: Vhi k0,k1, Vlo k0,k1
            int pa = vv & 1;
#pragma unroll
            for (int df = 0; df < 4; ++df) {
                s16x8 vf = *(const s16x8*)&Vs[df * 16 + lr][vv * 32 + lg * 8];
                oacc[df][0] = mfma16(vf, pfr[0][pa], oacc[df][0]);
                oacc[df][1] = mfma16(vf, pfr[1][pa], oacc[df][1]);
                if (vv < 2) {                        // V-hi also pairs with P-lo
                    oacc[df][0] = mfma16(vf, pfr[0][pa + 2], oacc[df][0]);
                    oacc[df][1] = mfma16(vf, pfr[1][pa + 2], oacc[df][1]);
                }
            }
        }
        __builtin_amdgcn_s_setprio(0);
        __syncthreads();
    }

    // epilogue: normalize, transpose O via per-wave LDS, write hi/lo planes
    float inv0 = 1.f / lrun[0], inv1 = 1.f / lrun[1];
    float* ow = (float*)&Ps[w][0];       // [32][68]
#pragma unroll
    for (int df = 0; df < 4; ++df) {
        f32x4 v0 = oacc[df][0] * inv0;
        f32x4 v1 = oacc[df][1] * inv1;
        *(f32x4*)&ow[(0 + lr) * 68 + df * 16 + lg * 4] = v0;
        *(f32x4*)&ow[(16 + lr) * 68 + df * 16 + lg * 4] = v1;
    }
#pragma unroll
    for (int pp = 0; pp < 2; ++pp) {
        int q = pp * 16 + (lane >> 2);
        int dc = (lane & 3) * 16;
        size_t gbase = (size_t)(b * 4096 + qbase + q) * 512 + h * 64 + dc;
        s16x8 hv0, hv1, lv0, lv1;
#pragma unroll
        for (int j = 0; j < 8; ++j) {
            float x = ow[q * 68 + dc + j];
            unsigned short hh = f2bf(x);
            hv0[j] = (short)hh; lv0[j] = (short)f2bf(x - bf2f(hh));
        }
#pragma unroll
        for (int j = 0; j < 8; ++j) {
            float x = ow[q * 68 + dc + 8 + j];
            unsigned short hh = f2bf(x);
            hv1[j] = (short)hh; lv1[j] = (short)f2bf(x - bf2f(hh));
        }
        *(s16x8*)&Ohi[gbase] = hv0;     *(s16x8*)&Ohi[gbase + 8] = hv1;
        *(s16x8*)&Olo[gbase] = lv0;     *(s16x8*)&Olo[gbase + 8] = lv1;
    }
}

// ---------------------------------------------------------------------------
extern "C" void kernel_launch(void* const* d_in, const int* in_sizes, int n_in,
                              void* d_out, int out_size, void* d_ws, size_t ws_size,
                              hipStream_t stream) {
    const float* x  = (const float*)d_in[0];
    const float* Wq = (const float*)d_in[1];
    const float* bq = (const float*)d_in[2];
    const float* Wk = (const float*)d_in[3];
    const float* bk = (const float*)d_in[4];
    const float* Wv = (const float*)d_in[5];
    const float* bv = (const float*)d_in[6];
    const float* Wo = (const float*)d_in[7];
    const float* bo = (const float*)d_in[8];
    float* out = (float*)d_out;

    char* ws = (char*)d_ws;
    const size_t PLANE = (size_t)8192 * 512 * 2;   // 8 MB (bf16 plane)
    const size_t WPL   = (size_t)512 * 512 * 2;    // 512 KB
    size_t off = 0;
    unsigned short* Xhi   = (unsigned short*)(ws + off); off += PLANE;
    unsigned short* Xlo   = (unsigned short*)(ws + off); off += PLANE;
    unsigned short* Wqthi = (unsigned short*)(ws + off); off += WPL;
    unsigned short* Wqtlo = (unsigned short*)(ws + off); off += WPL;
    unsigned short* Wkthi = (unsigned short*)(ws + off); off += WPL;
    unsigned short* Wktlo = (unsigned short*)(ws + off); off += WPL;
    unsigned short* Wvthi = (unsigned short*)(ws + off); off += WPL;
    unsigned short* Wvtlo = (unsigned short*)(ws + off); off += WPL;
    unsigned short* Wothi = (unsigned short*)(ws + off); off += WPL;
    unsigned short* Wotlo = (unsigned short*)(ws + off); off += WPL;
    unsigned short* Qhi   = (unsigned short*)(ws + off); off += PLANE;
    unsigned short* Qlo   = (unsigned short*)(ws + off); off += PLANE;
    unsigned short* Khi   = (unsigned short*)(ws + off); off += PLANE;
    unsigned short* Klo   = (unsigned short*)(ws + off); off += PLANE;
    unsigned short* Vhi   = (unsigned short*)(ws + off); off += PLANE;
    unsigned short* Vlo   = (unsigned short*)(ws + off); off += PLANE;
    unsigned short* Vthi  = (unsigned short*)(ws + off); off += PLANE;
    unsigned short* Vtlo  = (unsigned short*)(ws + off); off += PLANE;
    unsigned short* Ohi = Xhi;   // X is dead after the QKV GEMMs
    unsigned short* Olo = Xlo;

    k_split<<<1024, 256, 0, stream>>>(x, Xhi, Xlo, 8192 * 512 / 4);
    k_wsplit<<<64, 256, 0, stream>>>(Wq, Wqthi, Wqtlo, 0.125f);   // fold 1/sqrt(64) into Wq
    k_wsplit<<<64, 256, 0, stream>>>(Wk, Wkthi, Wktlo, 1.0f);
    k_wsplit<<<64, 256, 0, stream>>>(Wv, Wvthi, Wvtlo, 1.0f);
    k_wsplit<<<64, 256, 0, stream>>>(Wo, Wothi, Wotlo, 1.0f);
    k_gemm<0><<<256, 256, 0, stream>>>(Xhi, Xlo, Wqthi, Wqtlo, bq, 0.125f, Qhi, Qlo, nullptr);
    k_gemm<0><<<256, 256, 0, stream>>>(Xhi, Xlo, Wkthi, Wktlo, bk, 1.0f, Khi, Klo, nullptr);
    k_gemm<0><<<256, 256, 0, stream>>>(Xhi, Xlo, Wvthi, Wvtlo, bv, 1.0f, Vhi, Vlo, nullptr);
    k_vt<<<1024, 256, 0, stream>>>(Vhi, Vlo, Vthi, Vtlo);
    k_attn<<<512, 256, 0, stream>>>(Qhi, Qlo, Khi, Klo, Vthi, Vtlo, Ohi, Olo);
    k_gemm<1><<<256, 256, 0, stream>>>(Ohi, Olo, Wothi, Wotlo, bo, 1.0f, nullptr, nullptr, out);
}

// Round 5
// 403.520 us; speedup vs baseline: 1.2749x; 1.1958x over previous
//
#include <hip/hip_runtime.h>

#define DEV static __device__ __forceinline__

using f32x4 = __attribute__((ext_vector_type(4))) float;
using s16x8 = __attribute__((ext_vector_type(8))) short;   // 8 bf16 in 4 VGPRs

DEV unsigned short f2bf(float x) {          // fp32 -> bf16 bits, RNE
    unsigned int u = __float_as_uint(x);
    unsigned int r = (u + 0x7FFFu + ((u >> 16) & 1u)) >> 16;
    return (unsigned short)r;
}
DEV float bf2f(unsigned short u) {          // bf16 bits -> fp32 (exact)
    return __uint_as_float(((unsigned int)u) << 16);
}

DEV f32x4 mfma16(s16x8 a, s16x8 b, f32x4 c) {
    return __builtin_amdgcn_mfma_f32_16x16x32_bf16(a, b, c, 0, 0, 0);
}

DEV unsigned cvtpk_bf16(float a, float b) { // lo16 = bf16(a), hi16 = bf16(b)
    unsigned r;
    asm volatile("v_cvt_pk_bf16_f32 %0, %1, %2" : "=v"(r) : "v"(a), "v"(b));
    return r;
}

DEV void gload16(const unsigned short* g, short* l) {   // 16B global -> LDS direct
    __builtin_amdgcn_global_load_lds(
        (const __attribute__((address_space(1))) unsigned int*)g,
        (__attribute__((address_space(3))) unsigned int*)l, 16, 0, 0);
}

#define LOG2E 1.4426950408889634f

// ---------------------------------------------------------------------------
// split fp32 -> (hi, lo) bf16 planes
__global__ void k_split(const float* __restrict__ in, unsigned short* __restrict__ hi,
                        unsigned short* __restrict__ lo, int n4) {
    for (int i = blockIdx.x * blockDim.x + threadIdx.x; i < n4; i += gridDim.x * blockDim.x) {
        float4 v = ((const float4*)in)[i];
        ushort4 h, l;
        h.x = f2bf(v.x); l.x = f2bf(v.x - bf2f(h.x));
        h.y = f2bf(v.y); l.y = f2bf(v.y - bf2f(h.y));
        h.z = f2bf(v.z); l.z = f2bf(v.z - bf2f(h.z));
        h.w = f2bf(v.w); l.w = f2bf(v.w - bf2f(h.w));
        ((ushort4*)hi)[i] = h;
        ((ushort4*)lo)[i] = l;
    }
}

// ---------------------------------------------------------------------------
// W [512][512] (k-major) -> Wt hi/lo planes [n][k], with scale folded in.
__global__ void k_wsplit(const float* __restrict__ W, unsigned short* __restrict__ Thi,
                         unsigned short* __restrict__ Tlo, float scale) {
    __shared__ float tile[64][65];
    int bk = (blockIdx.x >> 3) * 64, bn = (blockIdx.x & 7) * 64;
    int t = threadIdx.x;
    int r = t >> 2, c4 = (t & 3) * 16;
#pragma unroll
    for (int j = 0; j < 16; j += 4) {
        float4 v = *(const float4*)&W[(size_t)(bk + r) * 512 + bn + c4 + j];
        tile[r][c4 + j + 0] = v.x; tile[r][c4 + j + 1] = v.y;
        tile[r][c4 + j + 2] = v.z; tile[r][c4 + j + 3] = v.w;
    }
    __syncthreads();
    int n = t >> 2, k4 = (t & 3) * 16;
#pragma unroll
    for (int j = 0; j < 16; ++j) {
        float x = tile[k4 + j][n] * scale;
        unsigned short h = f2bf(x);
        Thi[(size_t)(bn + n) * 512 + bk + k4 + j] = h;
        Tlo[(size_t)(bn + n) * 512 + bk + k4 + j] = f2bf(x - bf2f(h));
    }
}

// ---------------------------------------------------------------------------
// bias concat: [bq*qs | bk | bv] -> bcat[1536]
__global__ void k_bcat(const float* __restrict__ bq, const float* __restrict__ bk,
                       const float* __restrict__ bv, float* __restrict__ out, float qs) {
    int i = blockIdx.x * 256 + threadIdx.x;
    float v = (i < 512) ? bq[i] * qs : (i < 1024) ? bk[i - 512] : bv[i - 1024];
    out[i] = v;
}

// ---------------------------------------------------------------------------
// GEMM, 128x128 tile, BK=64, stacked-K' = 3*512: A segs [hi,hi,lo] x B segs [hi,lo,hi].
// LDS is XOR-swizzled (T2): data for global 16B-chunk g of row r lives at LDS chunk
// g ^ (r&7); achieved by pre-swizzling the global source column (global_load_lds
// writes linearly). Readers apply the same XOR.
// MODE 0: N'=1536, scatter bf16 hi/lo outputs to Q/K/V planes (bias = bcat).
// MODE 1: N=512, fp32 output (bias = bo).
template <int MODE>
__global__ __launch_bounds__(256, 2) void k_gemm2(
    const unsigned short* __restrict__ Ahi, const unsigned short* __restrict__ Alo,
    const unsigned short* __restrict__ Bhi, const unsigned short* __restrict__ Blo,
    const float* __restrict__ bias,
    unsigned short* __restrict__ Qh, unsigned short* __restrict__ Ql,
    unsigned short* __restrict__ Kh, unsigned short* __restrict__ Kl,
    unsigned short* __restrict__ Vh, unsigned short* __restrict__ Vl,
    float* __restrict__ Cf) {
    __shared__ short As[128 * 64];
    __shared__ short Bs[128 * 64];
    int t = threadIdx.x, lane = t & 63, w = t >> 6;
    int wr = w >> 1, wc = w & 1, lr = lane & 15, lg = lane >> 4;
    int bm = blockIdx.y * 128, bn = blockIdx.x * 128;
    f32x4 acc[4][4] = {};
    int srow = t >> 3;                       // 0..31 (4 passes of 32 rows)
    int sc = t & 7;                          // 16B chunk in row
    int gcol = (sc ^ (srow & 7)) * 8;        // pre-swizzled source col (shorts)
    int axr = (lr & 7) * 8;                  // reader-side XOR operand (shorts)
    for (int c = 0; c < 24; ++c) {
        int seg = c >> 3, kb = (c & 7) * 64;
        const unsigned short* Ap = (seg < 2) ? Ahi : Alo;
        const unsigned short* Bp = (seg == 1) ? Blo : Bhi;
        const unsigned short* ag = Ap + (size_t)(bm + srow) * 512 + kb + gcol;
        const unsigned short* bg = Bp + (size_t)(bn + srow) * 512 + kb + gcol;
#pragma unroll
        for (int ps = 0; ps < 4; ++ps) {
            gload16(ag + (size_t)ps * 32 * 512, &As[(srow + ps * 32) * 64 + sc * 8]);
            gload16(bg + (size_t)ps * 32 * 512, &Bs[(srow + ps * 32) * 64 + sc * 8]);
        }
        __syncthreads();
#pragma unroll
        for (int kk = 0; kk < 2; ++kk) {
            s16x8 af[4], bf[4];
#pragma unroll
            for (int i = 0; i < 4; ++i)
                af[i] = *(const s16x8*)&As[(wr * 64 + i * 16 + lr) * 64 + ((kk * 32 + lg * 8) ^ axr)];
#pragma unroll
            for (int i = 0; i < 4; ++i)
                bf[i] = *(const s16x8*)&Bs[(wc * 64 + i * 16 + lr) * 64 + ((kk * 32 + lg * 8) ^ axr)];
#pragma unroll
            for (int i = 0; i < 4; ++i)
#pragma unroll
                for (int j = 0; j < 4; ++j) acc[i][j] = mfma16(af[i], bf[j], acc[i][j]);
        }
        __syncthreads();
    }
#pragma unroll
    for (int i = 0; i < 4; ++i)
#pragma unroll
        for (int j = 0; j < 4; ++j) {
            int m = bm + wr * 64 + i * 16 + lg * 4;
            int n0 = bn + wc * 64 + j * 16;          // lr-independent base
            float bv = bias[n0 + lr];
            if (MODE == 0) {
                int sel = n0 >> 9;
                int col = (n0 & 511) + lr;
                unsigned short* Ph = (sel == 0) ? Qh : (sel == 1) ? Kh : Vh;
                unsigned short* Pl = (sel == 0) ? Ql : (sel == 1) ? Kl : Vl;
#pragma unroll
                for (int r = 0; r < 4; ++r) {
                    float v = acc[i][j][r] + bv;
                    unsigned short hh = f2bf(v);
                    Ph[(size_t)(m + r) * 512 + col] = hh;
                    Pl[(size_t)(m + r) * 512 + col] = f2bf(v - bf2f(hh));
                }
            } else {
#pragma unroll
                for (int r = 0; r < 4; ++r)
                    Cf[(size_t)(m + r) * 512 + n0 + lr] = acc[i][j][r] + bv;
            }
        }
}

// ---------------------------------------------------------------------------
// V planes [B*S][512] -> Vt planes [(b*8+h)*64 + d][4096]
__global__ void k_vt(const unsigned short* __restrict__ Vhi, const unsigned short* __restrict__ Vlo,
                     unsigned short* __restrict__ Vthi, unsigned short* __restrict__ Vtlo) {
    __shared__ unsigned short tile[64][72];
    int st = blockIdx.x & 63, bh = blockIdx.x >> 6;
    int b = bh >> 3, h = bh & 7;
    int t = threadIdx.x;
    int r = t >> 2, c = (t & 3) * 16;
    const unsigned short* src = Vhi;
    unsigned short* dst = Vthi;
#pragma unroll
    for (int pass = 0; pass < 2; ++pass) {
        size_t gin = (size_t)(b * 4096 + st * 64 + r) * 512 + h * 64 + c;
        *(s16x8*)&tile[r][c] = *(const s16x8*)&src[gin];
        *(s16x8*)&tile[r][c + 8] = *(const s16x8*)&src[gin + 8];
        __syncthreads();
        s16x8 o0, o1;
#pragma unroll
        for (int j = 0; j < 8; ++j) o0[j] = (short)tile[c + j][r];
#pragma unroll
        for (int j = 0; j < 8; ++j) o1[j] = (short)tile[c + 8 + j][r];
        size_t gout = (size_t)(bh * 64 + r) * 4096 + st * 64 + c;
        *(s16x8*)&dst[gout] = o0;
        *(s16x8*)&dst[gout + 8] = o1;
        __syncthreads();
        src = Vlo; dst = Vtlo;
    }
}

// ---------------------------------------------------------------------------
// Flash attention, exp2-domain scores (log2e folded into Wq/bq upstream).
// Q,K planes [B*S][512] (col = h*64+d); Vt planes [bh*64+d][4096].
// Block: 4 waves, each wave 32 q-rows; KBLK = 64. Reg-prefetched staging.
// Scores: mfma(a=K, b=Q) -> S[k][q], lane&15 = q. PV: mfma(a=Vt, b=P) -> O[d][q].
// P kept bf16-hi ONLY (PV = Vhi.P + Vlo.P); defer-max with THR=4 (p <= 16).
__global__ __launch_bounds__(256, 2) void k_attn(
    const unsigned short* __restrict__ Qhi, const unsigned short* __restrict__ Qlo,
    const unsigned short* __restrict__ Khi, const unsigned short* __restrict__ Klo,
    const unsigned short* __restrict__ Vthi, const unsigned short* __restrict__ Vtlo,
    unsigned short* __restrict__ Ohi, unsigned short* __restrict__ Olo) {
    __shared__ short Ks[64][136];        // cols [0:64] hi, [64:128] lo  (d')
    __shared__ short Vs[64][136];        // rows d, cols [0:64] k-hi, [64:128] k-lo
    __shared__ short Ps[4][2304];        // per-wave P [32][72] bf16-hi
    int t = threadIdx.x, lane = t & 63, w = t >> 6;
    int lr = lane & 15, lg = lane >> 4;
    int qt = blockIdx.x & 31, bh = blockIdx.x >> 5;
    int b = bh >> 3, h = bh & 7;
    int qbase = qt * 128 + w * 32;

    s16x8 qr[2][4];                      // [qf][hi0,hi1,lo0,lo1]
#pragma unroll
    for (int qf = 0; qf < 2; ++qf) {
        size_t mrow = (size_t)(b * 4096 + qbase + qf * 16 + lr) * 512 + h * 64;
        qr[qf][0] = *(const s16x8*)&Qhi[mrow + lg * 8];
        qr[qf][1] = *(const s16x8*)&Qhi[mrow + 32 + lg * 8];
        qr[qf][2] = *(const s16x8*)&Qlo[mrow + lg * 8];
        qr[qf][3] = *(const s16x8*)&Qlo[mrow + 32 + lg * 8];
    }

    f32x4 oacc[4][2] = {};
    float mrun[2] = {-1e30f, -1e30f}, lrun[2] = {0.f, 0.f};
    short* pw = &Ps[w][0];

    // staging bases: thread t covers (row = t>>2, plane/half-col p = t&3)
    int srow = t >> 2, p = t & 3;
    int db = (p & 1) * 32;
    const unsigned short* Kbase = ((p < 2) ? Khi : Klo) +
        (size_t)(b * 4096 + srow) * 512 + h * 64 + db;
    const unsigned short* Vbase = ((p < 2) ? Vthi : Vtlo) +
        (size_t)(bh * 64 + srow) * 4096 + db;

    s16x8 kst[4], vst[4];
    {   // prologue: load tile 0 into regs
        const unsigned short* kg = Kbase;
        const unsigned short* vg = Vbase;
        kst[0] = *(const s16x8*)(kg);      kst[1] = *(const s16x8*)(kg + 8);
        kst[2] = *(const s16x8*)(kg + 16); kst[3] = *(const s16x8*)(kg + 24);
        vst[0] = *(const s16x8*)(vg);      vst[1] = *(const s16x8*)(vg + 8);
        vst[2] = *(const s16x8*)(vg + 16); vst[3] = *(const s16x8*)(vg + 24);
    }

    for (int kt = 0; kt < 64; ++kt) {
        // write staged regs -> LDS
        *(s16x8*)&Ks[srow][p * 32 + 0] = kst[0];  *(s16x8*)&Ks[srow][p * 32 + 8] = kst[1];
        *(s16x8*)&Ks[srow][p * 32 + 16] = kst[2]; *(s16x8*)&Ks[srow][p * 32 + 24] = kst[3];
        *(s16x8*)&Vs[srow][p * 32 + 0] = vst[0];  *(s16x8*)&Vs[srow][p * 32 + 8] = vst[1];
        *(s16x8*)&Vs[srow][p * 32 + 16] = vst[2]; *(s16x8*)&Vs[srow][p * 32 + 24] = vst[3];
        // prefetch next tile into regs (lands under compute)
        {
            int ktn = (kt < 63) ? kt + 1 : 63;
            const unsigned short* kg = Kbase + (size_t)ktn * 64 * 512;
            const unsigned short* vg = Vbase + ktn * 64;
            kst[0] = *(const s16x8*)(kg);      kst[1] = *(const s16x8*)(kg + 8);
            kst[2] = *(const s16x8*)(kg + 16); kst[3] = *(const s16x8*)(kg + 24);
            vst[0] = *(const s16x8*)(vg);      vst[1] = *(const s16x8*)(vg + 8);
            vst[2] = *(const s16x8*)(vg + 16); vst[3] = *(const s16x8*)(vg + 24);
        }
        __syncthreads();

        // ---- scores: S[k][q] = Khi.Qhi + Klo.Qhi + Khi.Qlo (d-chunked) ----
        f32x4 sacc[4][2] = {};
        __builtin_amdgcn_s_setprio(1);
#pragma unroll
        for (int kk = 0; kk < 4; ++kk) {            // koff = kk*32: hi d0,d1, lo d0,d1
            int qa = kk & 1;
#pragma unroll
            for (int kf = 0; kf < 4; ++kf) {
                s16x8 af = *(const s16x8*)&Ks[kf * 16 + lr][kk * 32 + lg * 8];
                sacc[kf][0] = mfma16(af, qr[0][qa], sacc[kf][0]);
                sacc[kf][1] = mfma16(af, qr[1][qa], sacc[kf][1]);
                if (kk < 2) {                        // K-hi also pairs with Q-lo
                    sacc[kf][0] = mfma16(af, qr[0][qa + 2], sacc[kf][0]);
                    sacc[kf][1] = mfma16(af, qr[1][qa + 2], sacc[kf][1]);
                }
            }
        }
        __builtin_amdgcn_s_setprio(0);

        // ---- online softmax (exp2 domain, defer-max THR=4) + P pack (hi only) ----
#pragma unroll
        for (int qf = 0; qf < 2; ++qf) {
            float tmax = -1e30f;
#pragma unroll
            for (int kf = 0; kf < 4; ++kf)
#pragma unroll
                for (int r = 0; r < 4; ++r) tmax = fmaxf(tmax, sacc[kf][qf][r]);
            tmax = fmaxf(tmax, __shfl_xor(tmax, 16));
            tmax = fmaxf(tmax, __shfl_xor(tmax, 32));
            if (!__all(tmax <= mrun[qf] + 4.0f)) {   // rescale only when max grew
                float mnew = fmaxf(mrun[qf], tmax);
                float alpha = exp2f(mrun[qf] - mnew);
                mrun[qf] = mnew;
                lrun[qf] *= alpha;
#pragma unroll
                for (int df = 0; df < 4; ++df) oacc[df][qf] *= alpha;
            }
            float m = mrun[qf];
            float tsum = 0.f;
#pragma unroll
            for (int kf = 0; kf < 4; ++kf)
#pragma unroll
                for (int r = 0; r < 4; ++r) {
                    float pv = exp2f(sacc[kf][qf][r] - m);   // <= 2^4
                    sacc[kf][qf][r] = pv;
                    tsum += pv;
                }
            tsum += __shfl_xor(tsum, 16);
            tsum += __shfl_xor(tsum, 32);
            lrun[qf] += tsum;

            int q = qf * 16 + lr;
#pragma unroll
            for (int kf = 0; kf < 4; ++kf) {
                int kcol = kf * 16 + lg * 4;
                uint2 hv;
                hv.x = cvtpk_bf16(sacc[kf][qf][0], sacc[kf][qf][1]);
                hv.y = cvtpk_bf16(sacc[kf][qf][2], sacc[kf][qf][3]);
                *(uint2*)&pw[q * 72 + kcol] = hv;
            }
        }

        // ---- PV: O[d][q] += (Vhi + Vlo) . P ----
        s16x8 pfr[2][2];                  // [qf][k-half]
#pragma unroll
        for (int qf = 0; qf < 2; ++qf)
#pragma unroll
            for (int pp = 0; pp < 2; ++pp)
                pfr[qf][pp] = *(const s16x8*)&pw[(qf * 16 + lr) * 72 + pp * 32 + lg * 8];
        __builtin_amdgcn_s_setprio(1);
#pragma unroll
        for (int vv = 0; vv < 4; ++vv) {            // vv: Vhi k0,k1, Vlo k0,k1
            int pa = vv & 1;
#pragma unroll
            for (int df = 0; df < 4; ++df) {
                s16x8 vf = *(const s16x8*)&Vs[df * 16 + lr][vv * 32 + lg * 8];
                oacc[df][0] = mfma16(vf, pfr[0][pa], oacc[df][0]);
                oacc[df][1] = mfma16(vf, pfr[1][pa], oacc[df][1]);
            }
        }
        __builtin_amdgcn_s_setprio(0);
        __syncthreads();
    }

    // epilogue: normalize, transpose O via LDS (reuse Ks/Vs — all waves past
    // the final loop barrier), write hi/lo planes
    float inv0 = 1.f / lrun[0], inv1 = 1.f / lrun[1];
    short* eb = (w < 2) ? &Ks[0][0] : &Vs[0][0];
    float* ow = (float*)(eb + (w & 1) * 4352);   // [32][68] f32 per wave
#pragma unroll
    for (int df = 0; df < 4; ++df) {
        f32x4 v0 = oacc[df][0] * inv0;
        f32x4 v1 = oacc[df][1] * inv1;
        *(f32x4*)&ow[(0 + lr) * 68 + df * 16 + lg * 4] = v0;
        *(f32x4*)&ow[(16 + lr) * 68 + df * 16 + lg * 4] = v1;
    }
#pragma unroll
    for (int pp = 0; pp < 2; ++pp) {
        int q = pp * 16 + (lane >> 2);
        int dc = (lane & 3) * 16;
        size_t gbase = (size_t)(b * 4096 + qbase + q) * 512 + h * 64 + dc;
        s16x8 hv0, hv1, lv0, lv1;
#pragma unroll
        for (int j = 0; j < 8; ++j) {
            float x = ow[q * 68 + dc + j];
            unsigned short hh = f2bf(x);
            hv0[j] = (short)hh; lv0[j] = (short)f2bf(x - bf2f(hh));
        }
#pragma unroll
        for (int j = 0; j < 8; ++j) {
            float x = ow[q * 68 + dc + 8 + j];
            unsigned short hh = f2bf(x);
            hv1[j] = (short)hh; lv1[j] = (short)f2bf(x - bf2f(hh));
        }
        *(s16x8*)&Ohi[gbase] = hv0;     *(s16x8*)&Ohi[gbase + 8] = hv1;
        *(s16x8*)&Olo[gbase] = lv0;     *(s16x8*)&Olo[gbase + 8] = lv1;
    }
}

// ---------------------------------------------------------------------------
extern "C" void kernel_launch(void* const* d_in, const int* in_sizes, int n_in,
                              void* d_out, int out_size, void* d_ws, size_t ws_size,
                              hipStream_t stream) {
    const float* x  = (const float*)d_in[0];
    const float* Wq = (const float*)d_in[1];
    const float* bq = (const float*)d_in[2];
    const float* Wk = (const float*)d_in[3];
    const float* bk = (const float*)d_in[4];
    const float* Wv = (const float*)d_in[5];
    const float* bv = (const float*)d_in[6];
    const float* Wo = (const float*)d_in[7];
    const float* bo = (const float*)d_in[8];
    float* out = (float*)d_out;

    char* ws = (char*)d_ws;
    const size_t PLANE = (size_t)8192 * 512 * 2;   // 8 MB (bf16 plane)
    const size_t WBPL  = (size_t)1536 * 512 * 2;   // 1.5 MB (fused W planes)
    const size_t WPL   = (size_t)512 * 512 * 2;    // 512 KB
    size_t off = 0;
    unsigned short* Xhi   = (unsigned short*)(ws + off); off += PLANE;
    unsigned short* Xlo   = (unsigned short*)(ws + off); off += PLANE;
    unsigned short* WBhi  = (unsigned short*)(ws + off); off += WBPL;
    unsigned short* WBlo  = (unsigned short*)(ws + off); off += WBPL;
    unsigned short* Wothi = (unsigned short*)(ws + off); off += WPL;
    unsigned short* Wotlo = (unsigned short*)(ws + off); off += WPL;
    float*          bcat  = (float*)(ws + off);          off += 1536 * 4;
    unsigned short* Qhi   = (unsigned short*)(ws + off); off += PLANE;
    unsigned short* Qlo   = (unsigned short*)(ws + off); off += PLANE;
    unsigned short* Khi   = (unsigned short*)(ws + off); off += PLANE;
    unsigned short* Klo   = (unsigned short*)(ws + off); off += PLANE;
    unsigned short* Vhi   = (unsigned short*)(ws + off); off += PLANE;
    unsigned short* Vlo   = (unsigned short*)(ws + off); off += PLANE;
    unsigned short* Vthi  = (unsigned short*)(ws + off); off += PLANE;
    unsigned short* Vtlo  = (unsigned short*)(ws + off); off += PLANE;
    unsigned short* Ohi = Xhi;   // X is dead after the QKV GEMM
    unsigned short* Olo = Xlo;

    const float QS = 0.125f * LOG2E;   // 1/sqrt(64) * log2(e): exp2-domain scores

    k_split<<<1024, 256, 0, stream>>>(x, Xhi, Xlo, 8192 * 512 / 4);
    k_wsplit<<<64, 256, 0, stream>>>(Wq, WBhi,                 WBlo,                 QS);
    k_wsplit<<<64, 256, 0, stream>>>(Wk, WBhi + (size_t)512*512, WBlo + (size_t)512*512, 1.0f);
    k_wsplit<<<64, 256, 0, stream>>>(Wv, WBhi + (size_t)1024*512, WBlo + (size_t)1024*512, 1.0f);
    k_wsplit<<<64, 256, 0, stream>>>(Wo, Wothi, Wotlo, 1.0f);
    k_bcat<<<6, 256, 0, stream>>>(bq, bk, bv, bcat, QS);

    k_gemm2<0><<<dim3(12, 64), 256, 0, stream>>>(Xhi, Xlo, WBhi, WBlo, bcat,
                                                 Qhi, Qlo, Khi, Klo, Vhi, Vlo, nullptr);
    k_vt<<<1024, 256, 0, stream>>>(Vhi, Vlo, Vthi, Vtlo);
    k_attn<<<512, 256, 0, stream>>>(Qhi, Qlo, Khi, Klo, Vthi, Vtlo, Ohi, Olo);
    k_gemm2<1><<<dim3(4, 64), 256, 0, stream>>>(Ohi, Olo, Wothi, Wotlo, bo,
                                                nullptr, nullptr, nullptr, nullptr,
                                                nullptr, nullptr, out);
}

// Round 6
// 322.208 us; speedup vs baseline: 1.5967x; 1.2524x over previous
//
#include <hip/hip_runtime.h>

#define DEV static __device__ __forceinline__

using f32x4 = __attribute__((ext_vector_type(4))) float;
using s16x8 = __attribute__((ext_vector_type(8))) short;   // 8 bf16 in 4 VGPRs

DEV unsigned short f2bf(float x) {          // fp32 -> bf16 bits, RNE
    unsigned int u = __float_as_uint(x);
    unsigned int r = (u + 0x7FFFu + ((u >> 16) & 1u)) >> 16;
    return (unsigned short)r;
}
DEV float bf2f(unsigned short u) {          // bf16 bits -> fp32 (exact)
    return __uint_as_float(((unsigned int)u) << 16);
}

DEV f32x4 mfma16(s16x8 a, s16x8 b, f32x4 c) {
    return __builtin_amdgcn_mfma_f32_16x16x32_bf16(a, b, c, 0, 0, 0);
}

DEV unsigned cvtpk_bf16(float a, float b) { // lo16 = bf16(a), hi16 = bf16(b)
    unsigned r;
    asm volatile("v_cvt_pk_bf16_f32 %0, %1, %2" : "=v"(r) : "v"(a), "v"(b));
    return r;
}

DEV void gload16(const unsigned short* g, short* l) {   // 16B global -> LDS direct
    __builtin_amdgcn_global_load_lds(
        (const __attribute__((address_space(1))) unsigned int*)g,
        (__attribute__((address_space(3))) unsigned int*)l, 16, 0, 0);
}

#define LOG2E 1.4426950408889634f

// ---------------------------------------------------------------------------
// split fp32 -> (hi, lo) bf16 planes
__global__ void k_split(const float* __restrict__ in, unsigned short* __restrict__ hi,
                        unsigned short* __restrict__ lo, int n4) {
    for (int i = blockIdx.x * blockDim.x + threadIdx.x; i < n4; i += gridDim.x * blockDim.x) {
        float4 v = ((const float4*)in)[i];
        ushort4 h, l;
        h.x = f2bf(v.x); l.x = f2bf(v.x - bf2f(h.x));
        h.y = f2bf(v.y); l.y = f2bf(v.y - bf2f(h.y));
        h.z = f2bf(v.z); l.z = f2bf(v.z - bf2f(h.z));
        h.w = f2bf(v.w); l.w = f2bf(v.w - bf2f(h.w));
        ((ushort4*)hi)[i] = h;
        ((ushort4*)lo)[i] = l;
    }
}

// ---------------------------------------------------------------------------
// Fused weight prep: blocks 0..255 transpose+split the four 512x512 weights
// (Wq scaled by qs) into [n][k] hi/lo planes; blocks 256..261 build
// bcat = [bq*qs | bk | bv].
__global__ void k_wfuse(const float* __restrict__ Wq, const float* __restrict__ Wk,
                        const float* __restrict__ Wv, const float* __restrict__ Wo,
                        const float* __restrict__ bq, const float* __restrict__ bk,
                        const float* __restrict__ bv,
                        unsigned short* __restrict__ WBhi, unsigned short* __restrict__ WBlo,
                        unsigned short* __restrict__ Wothi, unsigned short* __restrict__ Wotlo,
                        float* __restrict__ bcat, float qs) {
    __shared__ float tile[64][65];
    int blk = blockIdx.x;
    if (blk >= 256) {
        int i = (blk - 256) * 256 + threadIdx.x;
        bcat[i] = (i < 512) ? bq[i] * qs : (i < 1024) ? bk[i - 512] : bv[i - 1024];
        return;
    }
    int wi = blk >> 6, sub = blk & 63;
    const float* W = (wi == 0) ? Wq : (wi == 1) ? Wk : (wi == 2) ? Wv : Wo;
    float scale = (wi == 0) ? qs : 1.0f;
    unsigned short* Thi = (wi < 3) ? WBhi + (size_t)wi * 512 * 512 : Wothi;
    unsigned short* Tlo = (wi < 3) ? WBlo + (size_t)wi * 512 * 512 : Wotlo;
    int bk0 = (sub >> 3) * 64, bn = (sub & 7) * 64;
    int t = threadIdx.x;
    int r = t >> 2, c4 = (t & 3) * 16;
#pragma unroll
    for (int j = 0; j < 16; j += 4) {
        float4 v = *(const float4*)&W[(size_t)(bk0 + r) * 512 + bn + c4 + j];
        tile[r][c4 + j + 0] = v.x; tile[r][c4 + j + 1] = v.y;
        tile[r][c4 + j + 2] = v.z; tile[r][c4 + j + 3] = v.w;
    }
    __syncthreads();
    int n = t >> 2, k4 = (t & 3) * 16;
#pragma unroll
    for (int j = 0; j < 16; ++j) {
        float x = tile[k4 + j][n] * scale;
        unsigned short h = f2bf(x);
        Thi[(size_t)(bn + n) * 512 + bk0 + k4 + j] = h;
        Tlo[(size_t)(bn + n) * 512 + bk0 + k4 + j] = f2bf(x - bf2f(h));
    }
}

// ---------------------------------------------------------------------------
// GEMM, 128x128 tile, BK=64, stacked-K' = 3*512: A segs [hi,hi,lo] x B segs [hi,lo,hi].
// LDS XOR-swizzled via pre-swizzled global source (global_load_lds writes linearly).
// MODE 0 (N'=1536): sel0 -> Qhi only; sel1 -> Khi+Klo; sel2 -> V written DIRECTLY
//   TRANSPOSED (bf16-hi) to Vt[(b*8+h)*64+d][4096] (fuses old k_vt).
// MODE 1 (N=512): fp32 output + bias.
template <int MODE>
__global__ __launch_bounds__(256, 2) void k_gemm2(
    const unsigned short* __restrict__ Ahi, const unsigned short* __restrict__ Alo,
    const unsigned short* __restrict__ Bhi, const unsigned short* __restrict__ Blo,
    const float* __restrict__ bias,
    unsigned short* __restrict__ Qh,
    unsigned short* __restrict__ Kh, unsigned short* __restrict__ Kl,
    unsigned short* __restrict__ Vt,
    float* __restrict__ Cf) {
    __shared__ short As[128 * 64];
    __shared__ short Bs[128 * 64];
    int t = threadIdx.x, lane = t & 63, w = t >> 6;
    int wr = w >> 1, wc = w & 1, lr = lane & 15, lg = lane >> 4;
    int bm = blockIdx.y * 128, bn = blockIdx.x * 128;
    f32x4 acc[4][4] = {};
    int srow = t >> 3;                       // 0..31 (4 passes of 32 rows)
    int sc = t & 7;                          // 16B chunk in row
    int gcol = (sc ^ (srow & 7)) * 8;        // pre-swizzled source col (shorts)
    int axr = (lr & 7) * 8;                  // reader-side XOR operand (shorts)
    for (int c = 0; c < 24; ++c) {
        int seg = c >> 3, kb = (c & 7) * 64;
        const unsigned short* Ap = (seg < 2) ? Ahi : Alo;
        const unsigned short* Bp = (seg == 1) ? Blo : Bhi;
        const unsigned short* ag = Ap + (size_t)(bm + srow) * 512 + kb + gcol;
        const unsigned short* bg = Bp + (size_t)(bn + srow) * 512 + kb + gcol;
#pragma unroll
        for (int ps = 0; ps < 4; ++ps) {
            gload16(ag + (size_t)ps * 32 * 512, &As[(srow + ps * 32) * 64 + sc * 8]);
            gload16(bg + (size_t)ps * 32 * 512, &Bs[(srow + ps * 32) * 64 + sc * 8]);
        }
        __syncthreads();
#pragma unroll
        for (int kk = 0; kk < 2; ++kk) {
            s16x8 af[4], bf[4];
#pragma unroll
            for (int i = 0; i < 4; ++i)
                af[i] = *(const s16x8*)&As[(wr * 64 + i * 16 + lr) * 64 + ((kk * 32 + lg * 8) ^ axr)];
#pragma unroll
            for (int i = 0; i < 4; ++i)
                bf[i] = *(const s16x8*)&Bs[(wc * 64 + i * 16 + lr) * 64 + ((kk * 32 + lg * 8) ^ axr)];
#pragma unroll
            for (int i = 0; i < 4; ++i)
#pragma unroll
                for (int j = 0; j < 4; ++j) acc[i][j] = mfma16(af[i], bf[j], acc[i][j]);
        }
        __syncthreads();
    }
    int sel = bn >> 9;   // block-uniform (128-wide tiles never straddle a 512 segment)
#pragma unroll
    for (int i = 0; i < 4; ++i)
#pragma unroll
        for (int j = 0; j < 4; ++j) {
            int m = bm + wr * 64 + i * 16 + lg * 4;
            int n0 = bn + wc * 64 + j * 16;          // lr-independent base
            float bv = bias[n0 + lr];
            if (MODE == 1) {
#pragma unroll
                for (int r = 0; r < 4; ++r)
                    Cf[(size_t)(m + r) * 512 + n0 + lr] = acc[i][j][r] + bv;
            } else if (sel == 0) {                   // Q: hi plane only
                int col = (n0 & 511) + lr;
#pragma unroll
                for (int r = 0; r < 4; ++r)
                    Qh[(size_t)(m + r) * 512 + col] = f2bf(acc[i][j][r] + bv);
            } else if (sel == 1) {                   // K: hi + lo planes
                int col = (n0 & 511) + lr;
#pragma unroll
                for (int r = 0; r < 4; ++r) {
                    float v = acc[i][j][r] + bv;
                    unsigned short hh = f2bf(v);
                    Kh[(size_t)(m + r) * 512 + col] = hh;
                    Kl[(size_t)(m + r) * 512 + col] = f2bf(v - bf2f(hh));
                }
            } else {                                 // V: transposed bf16-hi
                int nc = (n0 & 511) + lr;            // h*64 + d
                int bidx = m >> 12, s = m & 4095;    // 4 consecutive s = r
                size_t row = ((size_t)bidx * 8 + (nc >> 6)) * 64 + (nc & 63);
                uint2 pv;
                pv.x = cvtpk_bf16(acc[i][j][0] + bv, acc[i][j][1] + bv);
                pv.y = cvtpk_bf16(acc[i][j][2] + bv, acc[i][j][3] + bv);
                *(uint2*)&Vt[row * 4096 + s] = pv;
            }
        }
}

// ---------------------------------------------------------------------------
// Flash attention, exp2-domain scores (log2e folded into Wq/bq upstream).
// Q bf16-hi only; K hi+lo planes; V bf16-hi transposed [bh*64+d][4096].
// Block: 4 waves x 32 q-rows; KBLK = 64; reg-prefetched staging.
// Scores: mfma(a=K, b=Q) -> S[k][q], lane&15 = q. PV: mfma(a=Vt, b=P) -> O[d][q].
// Per kt per wave: 32 QK MFMA + 16 PV MFMA.
__global__ __launch_bounds__(256, 2) void k_attn(
    const unsigned short* __restrict__ Qhi,
    const unsigned short* __restrict__ Khi, const unsigned short* __restrict__ Klo,
    const unsigned short* __restrict__ Vthi,
    unsigned short* __restrict__ Ohi, unsigned short* __restrict__ Olo) {
    __shared__ short Ks[64][136];        // cols [0:64] hi, [64:128] lo  (d')
    __shared__ short Vs[64][72];         // rows d, cols k (single plane)
    __shared__ short Ps[4][2304];        // per-wave P [32][72] bf16
    int t = threadIdx.x, lane = t & 63, w = t >> 6;
    int lr = lane & 15, lg = lane >> 4;
    int qt = blockIdx.x & 31, bh = blockIdx.x >> 5;
    int b = bh >> 3, h = bh & 7;
    int qbase = qt * 128 + w * 32;

    s16x8 qr[2][2];                      // [qf][d-half], hi plane only
#pragma unroll
    for (int qf = 0; qf < 2; ++qf) {
        size_t mrow = (size_t)(b * 4096 + qbase + qf * 16 + lr) * 512 + h * 64;
        qr[qf][0] = *(const s16x8*)&Qhi[mrow + lg * 8];
        qr[qf][1] = *(const s16x8*)&Qhi[mrow + 32 + lg * 8];
    }

    f32x4 oacc[4][2] = {};
    float mrun[2] = {-1e30f, -1e30f}, lrun[2] = {0.f, 0.f};
    short* pw = &Ps[w][0];

    // staging: K: thread t -> (row = t>>2, p = t&3: hi/lo x d-half), 32 shorts
    //          V: thread t -> (row = t>>2, quarter = t&3), 16 shorts
    int srow = t >> 2, p = t & 3;
    int db = (p & 1) * 32;
    const unsigned short* Kbase = ((p < 2) ? Khi : Klo) +
        (size_t)(b * 4096 + srow) * 512 + h * 64 + db;
    const unsigned short* Vbase = Vthi + (size_t)(bh * 64 + srow) * 4096 + p * 16;

    s16x8 kst[4], vst[2];
    {   // prologue: tile 0
        kst[0] = *(const s16x8*)(Kbase);      kst[1] = *(const s16x8*)(Kbase + 8);
        kst[2] = *(const s16x8*)(Kbase + 16); kst[3] = *(const s16x8*)(Kbase + 24);
        vst[0] = *(const s16x8*)(Vbase);      vst[1] = *(const s16x8*)(Vbase + 8);
    }

    for (int kt = 0; kt < 64; ++kt) {
        *(s16x8*)&Ks[srow][p * 32 + 0] = kst[0];  *(s16x8*)&Ks[srow][p * 32 + 8] = kst[1];
        *(s16x8*)&Ks[srow][p * 32 + 16] = kst[2]; *(s16x8*)&Ks[srow][p * 32 + 24] = kst[3];
        *(s16x8*)&Vs[srow][p * 16 + 0] = vst[0];  *(s16x8*)&Vs[srow][p * 16 + 8] = vst[1];
        {   // prefetch next tile into regs (lands under compute)
            int ktn = (kt < 63) ? kt + 1 : 63;
            const unsigned short* kg = Kbase + (size_t)ktn * 64 * 512;
            const unsigned short* vg = Vbase + ktn * 64;
            kst[0] = *(const s16x8*)(kg);      kst[1] = *(const s16x8*)(kg + 8);
            kst[2] = *(const s16x8*)(kg + 16); kst[3] = *(const s16x8*)(kg + 24);
            vst[0] = *(const s16x8*)(vg);      vst[1] = *(const s16x8*)(vg + 8);
        }
        __syncthreads();

        // ---- scores: S[k][q] = (Khi + Klo) . Qhi ----
        f32x4 sacc[4][2] = {};
        __builtin_amdgcn_s_setprio(1);
#pragma unroll
        for (int kk = 0; kk < 4; ++kk) {            // kk: hi-d0, hi-d1, lo-d0, lo-d1
            int qa = kk & 1;
#pragma unroll
            for (int kf = 0; kf < 4; ++kf) {
                s16x8 af = *(const s16x8*)&Ks[kf * 16 + lr][kk * 32 + lg * 8];
                sacc[kf][0] = mfma16(af, qr[0][qa], sacc[kf][0]);
                sacc[kf][1] = mfma16(af, qr[1][qa], sacc[kf][1]);
            }
        }
        __builtin_amdgcn_s_setprio(0);

        // ---- online softmax (exp2 domain, defer-max THR=4) + P pack ----
#pragma unroll
        for (int qf = 0; qf < 2; ++qf) {
            float tmax = -1e30f;
#pragma unroll
            for (int kf = 0; kf < 4; ++kf)
#pragma unroll
                for (int r = 0; r < 4; ++r) tmax = fmaxf(tmax, sacc[kf][qf][r]);
            tmax = fmaxf(tmax, __shfl_xor(tmax, 16));
            tmax = fmaxf(tmax, __shfl_xor(tmax, 32));
            if (!__all(tmax <= mrun[qf] + 4.0f)) {   // rescale only when max grew
                float mnew = fmaxf(mrun[qf], tmax);
                float alpha = exp2f(mrun[qf] - mnew);
                mrun[qf] = mnew;
                lrun[qf] *= alpha;
#pragma unroll
                for (int df = 0; df < 4; ++df) oacc[df][qf] *= alpha;
            }
            float m = mrun[qf];
            float tsum = 0.f;
#pragma unroll
            for (int kf = 0; kf < 4; ++kf)
#pragma unroll
                for (int r = 0; r < 4; ++r) {
                    float pv = exp2f(sacc[kf][qf][r] - m);   // <= 2^4
                    sacc[kf][qf][r] = pv;
                    tsum += pv;
                }
            tsum += __shfl_xor(tsum, 16);
            tsum += __shfl_xor(tsum, 32);
            lrun[qf] += tsum;

            int q = qf * 16 + lr;
#pragma unroll
            for (int kf = 0; kf < 4; ++kf) {
                int kcol = kf * 16 + lg * 4;
                uint2 hv;
                hv.x = cvtpk_bf16(sacc[kf][qf][0], sacc[kf][qf][1]);
                hv.y = cvtpk_bf16(sacc[kf][qf][2], sacc[kf][qf][3]);
                *(uint2*)&pw[q * 72 + kcol] = hv;
            }
        }

        // ---- PV: O[d][q] += Vhi . P ----
        s16x8 pfr[2][2];                  // [qf][k-half]
#pragma unroll
        for (int qf = 0; qf < 2; ++qf)
#pragma unroll
            for (int pp = 0; pp < 2; ++pp)
                pfr[qf][pp] = *(const s16x8*)&pw[(qf * 16 + lr) * 72 + pp * 32 + lg * 8];
        __builtin_amdgcn_s_setprio(1);
#pragma unroll
        for (int vv = 0; vv < 2; ++vv) {
#pragma unroll
            for (int df = 0; df < 4; ++df) {
                s16x8 vf = *(const s16x8*)&Vs[df * 16 + lr][vv * 32 + lg * 8];
                oacc[df][0] = mfma16(vf, pfr[0][vv], oacc[df][0]);
                oacc[df][1] = mfma16(vf, pfr[1][vv], oacc[df][1]);
            }
        }
        __builtin_amdgcn_s_setprio(0);
        __syncthreads();
    }

    // epilogue: normalize, transpose O via LDS (reuse Ks for w0/w1, Ps for w2/w3 —
    // all loop reads done after final barrier; regions are per-wave so no extra sync),
    // write hi/lo planes
    float inv0 = 1.f / lrun[0], inv1 = 1.f / lrun[1];
    float* ow = ((w < 2) ? (float*)&Ks[0][0] : (float*)&Ps[0][0]) + (w & 1) * 2176; // [32][68]
#pragma unroll
    for (int df = 0; df < 4; ++df) {
        f32x4 v0 = oacc[df][0] * inv0;
        f32x4 v1 = oacc[df][1] * inv1;
        *(f32x4*)&ow[(0 + lr) * 68 + df * 16 + lg * 4] = v0;
        *(f32x4*)&ow[(16 + lr) * 68 + df * 16 + lg * 4] = v1;
    }
#pragma unroll
    for (int pp = 0; pp < 2; ++pp) {
        int q = pp * 16 + (lane >> 2);
        int dc = (lane & 3) * 16;
        size_t gbase = (size_t)(b * 4096 + qbase + q) * 512 + h * 64 + dc;
        s16x8 hv0, hv1, lv0, lv1;
#pragma unroll
        for (int j = 0; j < 8; ++j) {
            float x = ow[q * 68 + dc + j];
            unsigned short hh = f2bf(x);
            hv0[j] = (short)hh; lv0[j] = (short)f2bf(x - bf2f(hh));
        }
#pragma unroll
        for (int j = 0; j < 8; ++j) {
            float x = ow[q * 68 + dc + 8 + j];
            unsigned short hh = f2bf(x);
            hv1[j] = (short)hh; lv1[j] = (short)f2bf(x - bf2f(hh));
        }
        *(s16x8*)&Ohi[gbase] = hv0;     *(s16x8*)&Ohi[gbase + 8] = hv1;
        *(s16x8*)&Olo[gbase] = lv0;     *(s16x8*)&Olo[gbase + 8] = lv1;
    }
}

// ---------------------------------------------------------------------------
extern "C" void kernel_launch(void* const* d_in, const int* in_sizes, int n_in,
                              void* d_out, int out_size, void* d_ws, size_t ws_size,
                              hipStream_t stream) {
    const float* x  = (const float*)d_in[0];
    const float* Wq = (const float*)d_in[1];
    const float* bq = (const float*)d_in[2];
    const float* Wk = (const float*)d_in[3];
    const float* bk = (const float*)d_in[4];
    const float* Wv = (const float*)d_in[5];
    const float* bv = (const float*)d_in[6];
    const float* Wo = (const float*)d_in[7];
    const float* bo = (const float*)d_in[8];
    float* out = (float*)d_out;

    char* ws = (char*)d_ws;
    const size_t PLANE = (size_t)8192 * 512 * 2;   // 8 MB (bf16 plane)
    const size_t WBPL  = (size_t)1536 * 512 * 2;   // 1.5 MB (fused W planes)
    const size_t WPL   = (size_t)512 * 512 * 2;    // 512 KB
    size_t off = 0;
    unsigned short* Xhi   = (unsigned short*)(ws + off); off += PLANE;
    unsigned short* Xlo   = (unsigned short*)(ws + off); off += PLANE;
    unsigned short* WBhi  = (unsigned short*)(ws + off); off += WBPL;
    unsigned short* WBlo  = (unsigned short*)(ws + off); off += WBPL;
    unsigned short* Wothi = (unsigned short*)(ws + off); off += WPL;
    unsigned short* Wotlo = (unsigned short*)(ws + off); off += WPL;
    float*          bcat  = (float*)(ws + off);          off += 1536 * 4;
    unsigned short* Qhi   = (unsigned short*)(ws + off); off += PLANE;
    unsigned short* Khi   = (unsigned short*)(ws + off); off += PLANE;
    unsigned short* Klo   = (unsigned short*)(ws + off); off += PLANE;
    unsigned short* Vthi  = (unsigned short*)(ws + off); off += PLANE;
    unsigned short* Ohi = Xhi;   // X is dead after the QKV GEMM
    unsigned short* Olo = Xlo;

    const float QS = 0.125f * LOG2E;   // 1/sqrt(64) * log2(e): exp2-domain scores

    k_split<<<1024, 256, 0, stream>>>(x, Xhi, Xlo, 8192 * 512 / 4);
    k_wfuse<<<262, 256, 0, stream>>>(Wq, Wk, Wv, Wo, bq, bk, bv,
                                     WBhi, WBlo, Wothi, Wotlo, bcat, QS);
    k_gemm2<0><<<dim3(12, 64), 256, 0, stream>>>(Xhi, Xlo, WBhi, WBlo, bcat,
                                                 Qhi, Khi, Klo, Vthi, nullptr);
    k_attn<<<512, 256, 0, stream>>>(Qhi, Khi, Klo, Vthi, Ohi, Olo);
    k_gemm2<1><<<dim3(4, 64), 256, 0, stream>>>(Ohi, Olo, Wothi, Wotlo, bo,
                                                nullptr, nullptr, nullptr, nullptr, out);
}